// Round 1
// baseline (1995.457 us; speedup 1.0000x reference)
//
#include <hip/hip_runtime.h>

typedef unsigned short u16;
typedef __attribute__((ext_vector_type(8))) short short8;
typedef __attribute__((ext_vector_type(4))) float f32x4;

#define B_SZ 256
#define T_SZ 100
#define NIN  512
#define N_SZ 2048
#define KTOT 5632
#define KSPLIT 8
#define KCHUNK 704
#define NKT 11

// ws layout (bytes), all 256-aligned; total = 96,468,992
#define OFF_XSH  0ull
#define OFF_XSL  26214400ull
#define OFF_BC   52428800ull
#define OFF_SP0  75497472ull
#define OFF_SP1  76546048ull
#define OFF_MEM  77594624ull
#define OFF_PART 79691776ull

__device__ __forceinline__ u16 f2bf(float f){
    unsigned int x = __float_as_uint(f);
    x += 0x7fffu + ((x >> 16) & 1u);          // RNE to bf16
    return (u16)(x >> 16);
}
__device__ __forceinline__ float bf2f(u16 u){
    return __uint_as_float(((unsigned int)u) << 16);
}

// ---------------- prep kernels ----------------

// x [B][T][512] fp32 -> xh/xl [(t*256+b)*512+i] bf16 split
__global__ void split_x_k(const float* __restrict__ x, u16* __restrict__ xh, u16* __restrict__ xl){
    int idx = blockIdx.x * 256 + threadIdx.x;      // exactly 13,107,200 threads
    int b = idx / (T_SZ * NIN);
    int r = idx - b * (T_SZ * NIN);
    int tt = r >> 9;
    int i  = r & 511;
    float v = x[idx];
    u16 h = f2bf(v);
    float lo = v - bf2f(h);
    size_t o = ((size_t)tt * 256 + b) * 512 + i;
    xh[o] = h;
    xl[o] = f2bf(lo);
}

// W_fc [2048][512] -> Bc cols [4096..4608)=wh, [4608..5120)=wl, [5120..5632)=wh
__global__ void build_w_k(const float* __restrict__ Wfc, u16* __restrict__ Bc){
    int idx = blockIdx.x * 256 + threadIdx.x;      // exactly 1,048,576
    int m = idx >> 9, i = idx & 511;
    float v = Wfc[idx];
    u16 h = f2bf(v);
    float lo = v - bf2f(h);
    u16 l = f2bf(lo);
    size_t ro = (size_t)m * KTOT;
    Bc[ro + 4096 + i] = h;
    Bc[ro + 4608 + i] = l;
    Bc[ro + 5120 + i] = h;
}

// eff_rec[n][m] = rec*mask*binary; Bc[m][n] = hi, Bc[m][2048+n] = lo  (transpose via LDS)
__global__ void build_rec_k(const float* __restrict__ rec, const float* __restrict__ msk,
                            const float* __restrict__ bin, u16* __restrict__ Bc){
    __shared__ u16 hs[64][66];
    __shared__ u16 ls[64][66];
    int tid = threadIdx.x;
    int tm = tid & 63, t4 = tid >> 6;
    int m0 = blockIdx.x * 64, n0 = blockIdx.y * 64;
    #pragma unroll
    for (int j = 0; j < 16; ++j){
        int nl = t4 + j * 4;
        size_t gi = (size_t)(n0 + nl) * N_SZ + m0 + tm;
        float e = rec[gi] * msk[gi] * bin[gi];
        u16 h = f2bf(e);
        float lo = e - bf2f(h);
        hs[nl][tm] = h;
        ls[nl][tm] = f2bf(lo);
    }
    __syncthreads();
    #pragma unroll
    for (int j = 0; j < 16; ++j){
        int ml = t4 + j * 4;
        size_t o = (size_t)(m0 + ml) * KTOT + n0 + tm;
        Bc[o]        = hs[tm][ml];
        Bc[o + 2048] = ls[tm][ml];
    }
}

// ---------------- per-step GEMM ----------------
// out_partial[ks][b][n] = sum_{k in chunk ks} A[b][k] * Brow[n][k]
// A row b = [spike(2048)|spike(2048)|xh(512)|xh(512)|xl(512)] (virtual, region-mapped)
// Tiles: BM=128 (blockIdx.y), BN=128 (blockIdx.x), KSPLIT=8 (blockIdx.z), BK=64.
// 8 waves: 2 m-waves x 4 n-waves, wave tile 64x32, mfma_f32_16x16x32_bf16.
__global__ __launch_bounds__(512, 2) void gemm_step(
    const u16* __restrict__ Bc, const u16* __restrict__ spk,
    const u16* __restrict__ xh, const u16* __restrict__ xl,
    float* __restrict__ part)
{
    __shared__ u16 Ab[2][8192];   // [128 rows][64 k] bf16, XOR-swizzled
    __shared__ u16 Bb[2][8192];
    const int tid  = threadIdx.x;
    const int lane = tid & 63;
    const int w    = tid >> 6;
    const int l7 = lane & 7, l8 = lane >> 3;
    const int bn = blockIdx.x;
    const int my = blockIdx.y;
    const int ks = blockIdx.z;
    const int kbase = ks * KCHUNK;
    const int wm = w >> 2;   // 0..1
    const int wn = w & 3;    // 0..3

    auto load_tile = [&](int kt, short8* pa, short8* pb){
        int k0 = kbase + kt * 64;
        #pragma unroll
        for (int j = 0; j < 2; ++j){
            int chunk = w * 2 + j;           // 0..15
            int row = chunk * 8 + l8;        // 0..127
            int ce = l7 << 3;                // k element within tile
            int b = my * 128 + row;
            const u16* ga;
            if (k0 < 4096)      ga = spk + b * 2048 + ((k0 & 2047) + ce);
            else if (k0 < 5120) ga = xh + b * 512 + (((k0 - 4096) & 511) + ce);
            else                ga = xl + b * 512 + ((k0 - 5120) + ce);
            pa[j] = *reinterpret_cast<const short8*>(ga);
            const u16* gb = Bc + (size_t)(bn * 128 + row) * KTOT + (k0 + ce);
            pb[j] = *reinterpret_cast<const short8*>(gb);
        }
    };
    auto write_tile = [&](int sel, const short8* pa, const short8* pb){
        #pragma unroll
        for (int j = 0; j < 2; ++j){
            int chunk = w * 2 + j;
            int idx = chunk * 512 + l8 * 64 + ((l7 ^ l8) << 3);   // swizzled (u16 units)
            *reinterpret_cast<short8*>(&Ab[sel][idx]) = pa[j];
            *reinterpret_cast<short8*>(&Bb[sel][idx]) = pb[j];
        }
    };

    f32x4 zero = {0.f, 0.f, 0.f, 0.f};
    f32x4 acc[4][2];
    #pragma unroll
    for (int mi = 0; mi < 4; ++mi)
        #pragma unroll
        for (int ni = 0; ni < 2; ++ni) acc[mi][ni] = zero;

    short8 ra[2], rb[2], na[2], nb[2];
    load_tile(0, ra, rb);
    write_tile(0, ra, rb);
    __syncthreads();

    for (int kt = 0; kt < NKT; ++kt){
        int sel = kt & 1;
        if (kt + 1 < NKT) load_tile(kt + 1, na, nb);   // issue early (T14)
        #pragma unroll
        for (int kk2 = 0; kk2 < 2; ++kk2){
            int ke = kk2 * 32 + ((lane >> 4) << 3);    // k element for this lane group
            short8 af[4], bfr[2];
            #pragma unroll
            for (int mi = 0; mi < 4; ++mi){
                int row = wm * 64 + mi * 16 + (lane & 15);
                int byte = (row * 128 + ke * 2) ^ ((row & 7) << 4);
                af[mi] = *reinterpret_cast<const short8*>(
                    reinterpret_cast<const char*>(Ab[sel]) + byte);
            }
            #pragma unroll
            for (int ni = 0; ni < 2; ++ni){
                int row = wn * 32 + ni * 16 + (lane & 15);
                int byte = (row * 128 + ke * 2) ^ ((row & 7) << 4);
                bfr[ni] = *reinterpret_cast<const short8*>(
                    reinterpret_cast<const char*>(Bb[sel]) + byte);
            }
            #pragma unroll
            for (int mi = 0; mi < 4; ++mi)
                #pragma unroll
                for (int ni = 0; ni < 2; ++ni)
                    acc[mi][ni] = __builtin_amdgcn_mfma_f32_16x16x32_bf16(
                        af[mi], bfr[ni], acc[mi][ni], 0, 0, 0);
        }
        if (kt + 1 < NKT) write_tile((kt + 1) & 1, na, nb);  // write late, other buffer
        __syncthreads();
    }

    float* pp = part + (size_t)ks * (B_SZ * N_SZ);
    const int r4 = (lane >> 4) << 2;
    const int c  = lane & 15;
    #pragma unroll
    for (int mi = 0; mi < 4; ++mi){
        #pragma unroll
        for (int ni = 0; ni < 2; ++ni){
            int n = bn * 128 + wn * 32 + ni * 16 + c;
            #pragma unroll
            for (int jj = 0; jj < 4; ++jj){
                int b = my * 128 + wm * 64 + mi * 16 + r4 + jj;
                pp[(size_t)b * N_SZ + n] = acc[mi][ni][jj];
            }
        }
    }
}

// ---------------- combine + LIF ----------------
__global__ __launch_bounds__(256) void combine_step(
    const float* __restrict__ part, const u16* __restrict__ sc,
    u16* __restrict__ sn, float* __restrict__ memb,
    float* __restrict__ out, int t)
{
    int idx = blockIdx.x * 256 + threadIdx.x;     // exactly 524,288
    float cur = 0.f;
    #pragma unroll
    for (int ks = 0; ks < KSPLIT; ++ks)
        cur += part[(size_t)ks * (B_SZ * N_SZ) + idx];   // fixed order: deterministic
    float so = sc[idx] ? 1.f : 0.f;
    float m0 = memb[idx];
    float mn = 0.96f * m0 * (1.f - so) + cur;
    float s_new = (mn >= 1.0f) ? 1.f : 0.f;
    memb[idx] = mn;
    sn[idx] = (mn >= 1.0f) ? (u16)0x3F80 : (u16)0;
    int n = idx & 2047;
    if (n >= 2000){
        int b = idx >> 11;
        out[((size_t)b * T_SZ + t) * 48 + (n - 2000)] = s_new;
    }
}

// ---------------- host ----------------
extern "C" void kernel_launch(void* const* d_in, const int* in_sizes, int n_in,
                              void* d_out, int out_size, void* d_ws, size_t ws_size,
                              hipStream_t stream)
{
    const float* x   = (const float*)d_in[0];
    const float* Wfc = (const float*)d_in[1];
    const float* rec = (const float*)d_in[2];
    const float* msk = (const float*)d_in[3];
    const float* bin = (const float*)d_in[4];
    float* out = (float*)d_out;
    char* ws = (char*)d_ws;

    u16* xh    = (u16*)(ws + OFF_XSH);
    u16* xl    = (u16*)(ws + OFF_XSL);
    u16* Bc    = (u16*)(ws + OFF_BC);
    u16* sp0   = (u16*)(ws + OFF_SP0);
    u16* sp1   = (u16*)(ws + OFF_SP1);
    float* memb = (float*)(ws + OFF_MEM);
    float* part = (float*)(ws + OFF_PART);

    hipMemsetAsync(sp0, 0, (size_t)B_SZ * N_SZ * sizeof(u16), stream);
    hipMemsetAsync(memb, 0, (size_t)B_SZ * N_SZ * sizeof(float), stream);

    split_x_k<<<51200, 256, 0, stream>>>(x, xh, xl);
    build_w_k<<<4096, 256, 0, stream>>>(Wfc, Bc);
    build_rec_k<<<dim3(32, 32), 256, 0, stream>>>(rec, msk, bin, Bc);

    for (int t = 0; t < T_SZ; ++t){
        u16* sc  = (t & 1) ? sp1 : sp0;
        u16* snx = (t & 1) ? sp0 : sp1;
        gemm_step<<<dim3(16, 2, 8), 512, 0, stream>>>(
            Bc, sc, xh + (size_t)t * 131072, xl + (size_t)t * 131072, part);
        combine_step<<<2048, 256, 0, stream>>>(part, sc, snx, memb, out, t);
    }
}